// Round 1
// baseline (121249.878 us; speedup 1.0000x reference)
//
#include <hip/hip_runtime.h>
#include <hip/hip_bf16.h>
#include <math.h>

#define T_LEN   8192
#define D_IN    1024
#define H_DIM   1024
#define G4      4096      // 4*H
#define K_TAG   16
#define NWG     128       // workgroups in persistent LSTM kernel
#define NC      128       // CRF chunks
#define CLEN    64        // steps per CRF chunk
#define NEGINF_V (-100000.0f)

// ---------------------------------------------------------------------------
// init: bsum = b_ih + b_hh; h_all[0] = 0; flags = 0
// ---------------------------------------------------------------------------
__global__ void k_init(const float* __restrict__ b_ih, const float* __restrict__ b_hh,
                       float* __restrict__ bsum, float* __restrict__ h0,
                       int* __restrict__ flags) {
  int tid = blockIdx.x * 256 + threadIdx.x;
  if (tid < G4) bsum[tid] = b_ih[tid] + b_hh[tid];
  if (tid < H_DIM) h0[tid] = 0.f;
  if (tid < NWG) flags[tid] = 0;
}

// ---------------------------------------------------------------------------
// GEMM: xg[t][n] = sum_d seq[t][d]*W_ih[n][d] + bsum[n], stored bf16.
// 128x128 tile, K-tile 16, 256 threads, 8x8 per thread, fp32 vector ALU.
// ---------------------------------------------------------------------------
__global__ __launch_bounds__(256) void k_gemm_xg(
    const float* __restrict__ A,      // seq   (T, D)
    const float* __restrict__ B,      // W_ih  (4H, D)
    const float* __restrict__ bsum,   // (4H)
    __hip_bfloat16* __restrict__ xg)  // (T, 4H)
{
  __shared__ __align__(16) float As[16][132];
  __shared__ __align__(16) float Bs[16][132];
  const int tid = threadIdx.x;
  const int n0 = blockIdx.x * 128;   // 32 tiles
  const int m0 = blockIdx.y * 128;   // 64 tiles
  const int ty = tid >> 4, tx = tid & 15;
  float acc[8][8] = {};

  for (int k0 = 0; k0 < D_IN; k0 += 16) {
#pragma unroll
    for (int p0 = 0; p0 < 2; ++p0) {
      int p = tid + p0 * 256;              // 0..511 float4 slots
      int row = p >> 2;
      int c4 = (p & 3) * 4;
      float4 va = *(const float4*)&A[(size_t)(m0 + row) * D_IN + k0 + c4];
      As[c4 + 0][row] = va.x; As[c4 + 1][row] = va.y;
      As[c4 + 2][row] = va.z; As[c4 + 3][row] = va.w;
      float4 vb = *(const float4*)&B[(size_t)(n0 + row) * D_IN + k0 + c4];
      Bs[c4 + 0][row] = vb.x; Bs[c4 + 1][row] = vb.y;
      Bs[c4 + 2][row] = vb.z; Bs[c4 + 3][row] = vb.w;
    }
    __syncthreads();
#pragma unroll
    for (int k = 0; k < 16; ++k) {
      float4 a0 = *(const float4*)&As[k][ty * 8];
      float4 a1 = *(const float4*)&As[k][ty * 8 + 4];
      float4 b0 = *(const float4*)&Bs[k][tx * 8];
      float4 b1 = *(const float4*)&Bs[k][tx * 8 + 4];
      float av[8] = {a0.x, a0.y, a0.z, a0.w, a1.x, a1.y, a1.z, a1.w};
      float bv[8] = {b0.x, b0.y, b0.z, b0.w, b1.x, b1.y, b1.z, b1.w};
#pragma unroll
      for (int i = 0; i < 8; ++i)
#pragma unroll
        for (int j = 0; j < 8; ++j)
          acc[i][j] = fmaf(av[i], bv[j], acc[i][j]);
    }
    __syncthreads();
  }

#pragma unroll
  for (int i = 0; i < 8; ++i) {
    size_t m = (size_t)(m0 + ty * 8 + i);
    union { __hip_bfloat16 h[8]; uint4 v; } pk;
#pragma unroll
    for (int j = 0; j < 8; ++j)
      pk.h[j] = __float2bfloat16(acc[i][j] + bsum[n0 + tx * 8 + j]);
    *(uint4*)&xg[m * G4 + n0 + tx * 8] = pk.v;
  }
}

// ---------------------------------------------------------------------------
// Persistent LSTM recurrence. 128 WGs x 256 threads, all co-resident.
// WG w owns h[w*8 .. w*8+8) and gate rows {q*1024 + w*8 + r}.
// Thread t: rl=t>>3 (0..31 local gate row), sub=t&7 (column chunk).
// Weights for its 128 columns (col = sub*4 + 32k + c) live in registers.
// ---------------------------------------------------------------------------
__global__ __launch_bounds__(256) void k_lstm(
    const float* __restrict__ W_hh,          // (4H, H)
    const __hip_bfloat16* __restrict__ xg,   // (T, 4H)
    float* __restrict__ h_all,               // (T+1, H)
    int* __restrict__ flags)                 // (NWG)
{
  __shared__ __align__(16) float h_lds[H_DIM];
  __shared__ float gates[32];
  __shared__ float c_sl[8];

  const int tid = threadIdx.x;
  const int w = blockIdx.x;
  const int rl = tid >> 3;          // 0..31
  const int sub = tid & 7;          // 0..7
  const int q = rl >> 3, r = rl & 7;
  const int grow = q * H_DIM + w * 8 + r;

  float4 w4[32];
#pragma unroll
  for (int k = 0; k < 32; ++k)
    w4[k] = *(const float4*)&W_hh[(size_t)grow * H_DIM + sub * 4 + 32 * k];

  if (tid < 8) c_sl[tid] = 0.f;
  __syncthreads();

  for (int t = 1; t <= T_LEN; ++t) {
    // ---- wait for h_{t-1} published by all WGs ----
    if (tid < NWG && tid != w) {
      while (__hip_atomic_load(&flags[tid], __ATOMIC_RELAXED,
                               __HIP_MEMORY_SCOPE_AGENT) < t - 1)
        __builtin_amdgcn_s_sleep(1);
    }
    __syncthreads();
    __threadfence();   // acquire: make other-XCD h stores visible

    // ---- load h_{t-1} into LDS ----
    ((float4*)h_lds)[tid] = ((const float4*)(h_all + (size_t)(t - 1) * H_DIM))[tid];
    __syncthreads();

    // ---- matvec: 128 columns per thread ----
    float acc = 0.f;
#pragma unroll
    for (int k = 0; k < 32; ++k) {
      float4 hv = ((const float4*)h_lds)[sub + 8 * k];
      acc = fmaf(w4[k].x, hv.x, acc);
      acc = fmaf(w4[k].y, hv.y, acc);
      acc = fmaf(w4[k].z, hv.z, acc);
      acc = fmaf(w4[k].w, hv.w, acc);
    }
    acc += __shfl_xor(acc, 1);
    acc += __shfl_xor(acc, 2);
    acc += __shfl_xor(acc, 4);
    if (sub == 0)
      gates[rl] = acc + __bfloat162float(xg[(size_t)(t - 1) * G4 + grow]);
    __syncthreads();

    // ---- nonlinearity + state update (8 threads) ----
    if (tid < 8) {
      float gi = gates[tid],      gf = gates[8 + tid];
      float gg = gates[16 + tid], go = gates[24 + tid];
      float si = 1.f / (1.f + expf(-gi));
      float sf = 1.f / (1.f + expf(-gf));
      float so = 1.f / (1.f + expf(-go));
      float c = sf * c_sl[tid] + si * tanhf(gg);
      c_sl[tid] = c;
      float h = so * tanhf(c);
      h_all[(size_t)t * H_DIM + w * 8 + tid] = h;
    }
    // stores above are wave 0 lanes 0..7; lane 0 fences + publishes
    if (tid == 0) {
      __threadfence();
      __hip_atomic_store(&flags[w], t, __ATOMIC_RELAXED, __HIP_MEMORY_SCOPE_AGENT);
    }
    __syncthreads();
  }
}

// ---------------------------------------------------------------------------
// 16-lane logsumexp reduce (lanes grouped by tid&15 within a wave)
// ---------------------------------------------------------------------------
__device__ __forceinline__ float lse16(float v) {
  float m = v;
  m = fmaxf(m, __shfl_xor(m, 1));
  m = fmaxf(m, __shfl_xor(m, 2));
  m = fmaxf(m, __shfl_xor(m, 4));
  m = fmaxf(m, __shfl_xor(m, 8));
  float e = expf(v - m);
  e += __shfl_xor(e, 1);
  e += __shfl_xor(e, 2);
  e += __shfl_xor(e, 4);
  e += __shfl_xor(e, 8);
  return m + logf(e);
}

// ---------------------------------------------------------------------------
// CRF chunk kernel: per chunk c, compute feat rows s=c*64+1..c*64+64 and the
// chunk's log-semiring matrix product P_c = M_{c*64+1} x ... x M_{c*64+64}.
// M_s[i][j] = trans[i][j] + feat[s][j], feat[s] from h_all[s].
// ---------------------------------------------------------------------------
__global__ __launch_bounds__(256) void k_chunk(
    const float* __restrict__ h_all,
    const float* __restrict__ W_tag, const float* __restrict__ b_tag,
    const float* __restrict__ trans,
    float* __restrict__ featbuf,   // (T+1, 16), rows 1..T written
    float* __restrict__ Pbuf)      // (NC, 256)
{
  __shared__ float trs[16][17];
  __shared__ float featc[CLEN][16];
  __shared__ __align__(16) float hrow[H_DIM];
  __shared__ float red[16][17];
  __shared__ float Pa[16][17], Pb[16][17];

  const int tid = threadIdx.x;
  const int c = blockIdx.x;
  trs[tid >> 4][tid & 15] = trans[tid];

  // ---- feat phase ----
  const int jj = tid & 15, part = tid >> 4;
  for (int u = 0; u < CLEN; ++u) {
    int s = c * CLEN + 1 + u;
    ((float4*)hrow)[tid] = ((const float4*)(h_all + (size_t)s * H_DIM))[tid];
    __syncthreads();
    const float* wt = W_tag + (size_t)jj * H_DIM + part * 64;
    const float* hp = hrow + part * 64;
    float4 a4 = {0.f, 0.f, 0.f, 0.f};
#pragma unroll
    for (int k2 = 0; k2 < 64; k2 += 4) {
      float4 hv = *(const float4*)(hp + k2);
      float4 wv = *(const float4*)(wt + k2);
      a4.x = fmaf(hv.x, wv.x, a4.x);
      a4.y = fmaf(hv.y, wv.y, a4.y);
      a4.z = fmaf(hv.z, wv.z, a4.z);
      a4.w = fmaf(hv.w, wv.w, a4.w);
    }
    red[jj][part] = (a4.x + a4.y) + (a4.z + a4.w);
    __syncthreads();
    if (tid < 16) {
      float ssum = b_tag[tid];
#pragma unroll
      for (int pp = 0; pp < 16; ++pp) ssum += red[tid][pp];
      featc[u][tid] = ssum;
      featbuf[(size_t)s * K_TAG + tid] = ssum;
    }
    __syncthreads();
  }

  // ---- chunk product phase ----
  const int i = tid >> 4, j = tid & 15;
  Pa[i][j] = trs[i][j] + featc[0][j];
  __syncthreads();
  float* Pr = &Pa[0][0];
  float* Pw = &Pb[0][0];
  for (int u = 1; u < CLEN; ++u) {
    float fj = featc[u][j];
    float m = -3.0e38f;
#pragma unroll
    for (int k = 0; k < 16; ++k) m = fmaxf(m, Pr[i * 17 + k] + trs[k][j]);
    float e = 0.f;
#pragma unroll
    for (int k = 0; k < 16; ++k) e += expf(Pr[i * 17 + k] + trs[k][j] - m);
    Pw[i * 17 + j] = m + fj + logf(e);
    __syncthreads();
    float* tsw = Pr; Pr = Pw; Pw = tsw;
  }
  Pbuf[(size_t)c * 256 + i * 16 + j] = Pr[i * 17 + j];
}

// ---------------------------------------------------------------------------
// Sequential scan over chunk matrices (1 WG): boundary alphas + Z + alpha row 0
// ---------------------------------------------------------------------------
__global__ __launch_bounds__(256) void k_scan(
    const float* __restrict__ Pbuf,
    float* __restrict__ bbuf,      // (NC+1, 16)
    float* __restrict__ out)
{
  __shared__ float Pl[16][17];
  __shared__ float bcur[16], bnew[16];
  const int tid = threadIdx.x;
  const int i = tid & 15, j = tid >> 4;
  if (tid < 16) {
    float a0 = (tid == 0) ? 0.f : NEGINF_V;
    bcur[tid] = a0;
    bbuf[tid] = a0;
    out[1 + tid] = a0;             // alpha row 0
  }
  __syncthreads();
  for (int c = 0; c < NC; ++c) {
    Pl[tid >> 4][tid & 15] = Pbuf[(size_t)c * 256 + tid];
    __syncthreads();
    float r_ = lse16(bcur[i] + Pl[i][j]);
    if (i == 0) bnew[j] = r_;
    __syncthreads();
    if (tid < 16) {
      bcur[tid] = bnew[tid];
      bbuf[(size_t)(c + 1) * K_TAG + tid] = bnew[tid];
    }
    __syncthreads();
  }
  if (tid < 16) {
    float z = lse16(bcur[tid]);
    if (tid == 0) out[0] = z;
  }
}

// ---------------------------------------------------------------------------
// Replay within each chunk: write alpha rows s = c*64+1 .. c*64+64
// ---------------------------------------------------------------------------
__global__ __launch_bounds__(256) void k_alpha(
    const float* __restrict__ featbuf, const float* __restrict__ trans,
    const float* __restrict__ bbuf, float* __restrict__ out)
{
  __shared__ float trs[16][17];
  __shared__ float acur[16], anew[16];
  const int tid = threadIdx.x;
  const int c = blockIdx.x;
  trs[tid >> 4][tid & 15] = trans[tid];
  if (tid < 16) acur[tid] = bbuf[(size_t)c * K_TAG + tid];
  __syncthreads();
  const int i = tid & 15, j = tid >> 4;
  for (int u = 0; u < CLEN; ++u) {
    int s = c * CLEN + 1 + u;
    float v = acur[i] + trs[i][j] + featbuf[(size_t)s * K_TAG + j];
    float r_ = lse16(v);
    if (i == 0) anew[j] = r_;
    __syncthreads();
    if (tid < 16) {
      acur[tid] = anew[tid];
      out[1 + (size_t)s * K_TAG + tid] = anew[tid];
    }
    __syncthreads();
  }
}

// ---------------------------------------------------------------------------
extern "C" void kernel_launch(void* const* d_in, const int* in_sizes, int n_in,
                              void* d_out, int out_size, void* d_ws, size_t ws_size,
                              hipStream_t stream) {
  (void)in_sizes; (void)n_in; (void)out_size; (void)ws_size;
  const float* seq   = (const float*)d_in[0];
  const float* W_ih  = (const float*)d_in[1];
  const float* W_hh  = (const float*)d_in[2];
  const float* b_ih  = (const float*)d_in[3];
  const float* b_hh  = (const float*)d_in[4];
  const float* W_tag = (const float*)d_in[5];
  const float* b_tag = (const float*)d_in[6];
  const float* trans = (const float*)d_in[7];
  float* out = (float*)d_out;

  char* base = (char*)d_ws;
  size_t off = 0;
  auto take = [&](size_t nbytes) -> void* {
    void* p = base + off;
    off += (nbytes + 255) & ~(size_t)255;
    return p;
  };
  __hip_bfloat16* xg = (__hip_bfloat16*)take((size_t)T_LEN * G4 * sizeof(__hip_bfloat16));
  float* h_all   = (float*)take((size_t)(T_LEN + 1) * H_DIM * sizeof(float));
  float* featbuf = (float*)take((size_t)(T_LEN + 1) * K_TAG * sizeof(float));
  float* Pbuf    = (float*)take((size_t)NC * 256 * sizeof(float));
  float* bbuf    = (float*)take((size_t)(NC + 1) * K_TAG * sizeof(float));
  float* bsum    = (float*)take((size_t)G4 * sizeof(float));
  int*   flags   = (int*)take((size_t)NWG * sizeof(int));

  k_init<<<16, 256, 0, stream>>>(b_ih, b_hh, bsum, h_all, flags);
  k_gemm_xg<<<dim3(G4 / 128, T_LEN / 128), 256, 0, stream>>>(seq, W_ih, bsum, xg);
  k_lstm<<<NWG, 256, 0, stream>>>(W_hh, xg, h_all, flags);
  k_chunk<<<NC, 256, 0, stream>>>(h_all, W_tag, b_tag, trans, featbuf, Pbuf);
  k_scan<<<1, 256, 0, stream>>>(Pbuf, bbuf, out);
  k_alpha<<<NC, 256, 0, stream>>>(featbuf, trans, bbuf, out);
}

// Round 2
// 23310.823 us; speedup vs baseline: 5.2014x; 5.2014x over previous
//
#include <hip/hip_runtime.h>
#include <hip/hip_bf16.h>
#include <math.h>

#define T_LEN   8192
#define D_IN    1024
#define H_DIM   1024
#define G4      4096      // 4*H
#define K_TAG   16
#define NWG     128       // workgroups in persistent LSTM kernel
#define NC      128       // CRF chunks
#define CLEN    64        // steps per CRF chunk
#define NEGINF_V (-100000.0f)

// ---------------------------------------------------------------------------
// init: bsum = b_ih + b_hh; h_all[0] = 0; htag[2][1024] = {tag 0, val 0}
// MUST run every launch: graph replays would otherwise see stale tags.
// ---------------------------------------------------------------------------
__global__ void k_init(const float* __restrict__ b_ih, const float* __restrict__ b_hh,
                       float* __restrict__ bsum, float* __restrict__ h0,
                       unsigned long long* __restrict__ htag) {
  int tid = blockIdx.x * 256 + threadIdx.x;
  if (tid < G4) bsum[tid] = b_ih[tid] + b_hh[tid];
  if (tid < H_DIM) h0[tid] = 0.f;
  if (tid < 2 * H_DIM) htag[tid] = 0ULL;   // tag=0, value=0.0f
}

// ---------------------------------------------------------------------------
// GEMM: xg[t][n] = sum_d seq[t][d]*W_ih[n][d] + bsum[n], stored bf16.
// 128x128 tile, K-tile 16, 256 threads, 8x8 per thread, fp32 vector ALU.
// ---------------------------------------------------------------------------
__global__ __launch_bounds__(256) void k_gemm_xg(
    const float* __restrict__ A,      // seq   (T, D)
    const float* __restrict__ B,      // W_ih  (4H, D)
    const float* __restrict__ bsum,   // (4H)
    __hip_bfloat16* __restrict__ xg)  // (T, 4H)
{
  __shared__ __align__(16) float As[16][132];
  __shared__ __align__(16) float Bs[16][132];
  const int tid = threadIdx.x;
  const int n0 = blockIdx.x * 128;   // 32 tiles
  const int m0 = blockIdx.y * 128;   // 64 tiles
  const int ty = tid >> 4, tx = tid & 15;
  float acc[8][8] = {};

  for (int k0 = 0; k0 < D_IN; k0 += 16) {
#pragma unroll
    for (int p0 = 0; p0 < 2; ++p0) {
      int p = tid + p0 * 256;              // 0..511 float4 slots
      int row = p >> 2;
      int c4 = (p & 3) * 4;
      float4 va = *(const float4*)&A[(size_t)(m0 + row) * D_IN + k0 + c4];
      As[c4 + 0][row] = va.x; As[c4 + 1][row] = va.y;
      As[c4 + 2][row] = va.z; As[c4 + 3][row] = va.w;
      float4 vb = *(const float4*)&B[(size_t)(n0 + row) * D_IN + k0 + c4];
      Bs[c4 + 0][row] = vb.x; Bs[c4 + 1][row] = vb.y;
      Bs[c4 + 2][row] = vb.z; Bs[c4 + 3][row] = vb.w;
    }
    __syncthreads();
#pragma unroll
    for (int k = 0; k < 16; ++k) {
      float4 a0 = *(const float4*)&As[k][ty * 8];
      float4 a1 = *(const float4*)&As[k][ty * 8 + 4];
      float4 b0 = *(const float4*)&Bs[k][tx * 8];
      float4 b1 = *(const float4*)&Bs[k][tx * 8 + 4];
      float av[8] = {a0.x, a0.y, a0.z, a0.w, a1.x, a1.y, a1.z, a1.w};
      float bv[8] = {b0.x, b0.y, b0.z, b0.w, b1.x, b1.y, b1.z, b1.w};
#pragma unroll
      for (int i = 0; i < 8; ++i)
#pragma unroll
        for (int j = 0; j < 8; ++j)
          acc[i][j] = fmaf(av[i], bv[j], acc[i][j]);
    }
    __syncthreads();
  }

#pragma unroll
  for (int i = 0; i < 8; ++i) {
    size_t m = (size_t)(m0 + ty * 8 + i);
    union { __hip_bfloat16 h[8]; uint4 v; } pk;
#pragma unroll
    for (int j = 0; j < 8; ++j)
      pk.h[j] = __float2bfloat16(acc[i][j] + bsum[n0 + tx * 8 + j]);
    *(uint4*)&xg[m * G4 + n0 + tx * 8] = pk.v;
  }
}

// ---------------------------------------------------------------------------
// Persistent LSTM recurrence — fence-free tagged exchange.
// 128 WGs x 256 threads. WG w owns h[w*8 .. w*8+8) and gate rows
// {q*1024 + w*8 + r}. Thread t: rl=t>>3 (local gate row), sub=t&7.
// Weights for its 128 columns (col = sub*4 + 32k + c) live in registers.
//
// h exchange: htag[parity][e] = {u32 tag = t, u32 bits = f32 h_e}, written
// and read as single 64-bit relaxed AGENT-scope atomics (bypass the
// non-coherent XCD L2 -> coherent point). tag+value arrive atomically, so
// NO __threadfence and NO separate flag array. Double-buffered by t&1:
// a writer reaches step t+1 (same parity as t-1) only after reading every
// WG's step-t output, which that WG published only after consuming t-1 —
// so a pending reader's t-1 slot is never overwritten.
// ---------------------------------------------------------------------------
__global__ __launch_bounds__(256) void k_lstm(
    const float* __restrict__ W_hh,          // (4H, H)
    const __hip_bfloat16* __restrict__ xg,   // (T, 4H)
    float* __restrict__ h_all,               // (T+1, H) plain, for CRF kernels
    unsigned long long* __restrict__ htag)   // (2, H) tagged exchange
{
  __shared__ __align__(16) float h_lds[H_DIM];
  __shared__ float gates[32];
  __shared__ float c_sl[8];

  const int tid = threadIdx.x;
  const int w = blockIdx.x;
  const int rl = tid >> 3;          // 0..31
  const int sub = tid & 7;          // 0..7
  const int q = rl >> 3, r = rl & 7;
  const int grow = q * H_DIM + w * 8 + r;
  const int e = tid * 4;            // this thread's 4 exchange elements

  float4 w4[32];
#pragma unroll
  for (int k = 0; k < 32; ++k)
    w4[k] = *(const float4*)&W_hh[(size_t)grow * H_DIM + sub * 4 + 32 * k];

  if (tid < 8) c_sl[tid] = 0.f;
  __syncthreads();

  for (int t = 1; t <= T_LEN; ++t) {
    // prefetch this step's input-gate term (independent of h exchange)
    float xgv = 0.f;
    if (sub == 0)
      xgv = __bfloat162float(xg[(size_t)(t - 1) * G4 + grow]);

    // ---- poll tagged h_{t-1} (4 u64 per thread) ----
    unsigned long long* hb = htag + (((t - 1) & 1) << 10);
    const unsigned tgt = (unsigned)(t - 1);
    unsigned long long x0, x1, x2, x3;
    for (;;) {
      x0 = __hip_atomic_load(hb + e + 0, __ATOMIC_RELAXED, __HIP_MEMORY_SCOPE_AGENT);
      x1 = __hip_atomic_load(hb + e + 1, __ATOMIC_RELAXED, __HIP_MEMORY_SCOPE_AGENT);
      x2 = __hip_atomic_load(hb + e + 2, __ATOMIC_RELAXED, __HIP_MEMORY_SCOPE_AGENT);
      x3 = __hip_atomic_load(hb + e + 3, __ATOMIC_RELAXED, __HIP_MEMORY_SCOPE_AGENT);
      unsigned t0 = (unsigned)(x0 >> 32), t1 = (unsigned)(x1 >> 32);
      unsigned t2 = (unsigned)(x2 >> 32), t3 = (unsigned)(x3 >> 32);
      unsigned mn = min(min(t0, t1), min(t2, t3));
      if (mn >= tgt) break;
      __builtin_amdgcn_s_sleep(1);
    }
    h_lds[e + 0] = __uint_as_float((unsigned)x0);
    h_lds[e + 1] = __uint_as_float((unsigned)x1);
    h_lds[e + 2] = __uint_as_float((unsigned)x2);
    h_lds[e + 3] = __uint_as_float((unsigned)x3);
    __syncthreads();

    // ---- matvec: 128 columns per thread ----
    float acc = 0.f;
#pragma unroll
    for (int k = 0; k < 32; ++k) {
      float4 hv = ((const float4*)h_lds)[sub + 8 * k];
      acc = fmaf(w4[k].x, hv.x, acc);
      acc = fmaf(w4[k].y, hv.y, acc);
      acc = fmaf(w4[k].z, hv.z, acc);
      acc = fmaf(w4[k].w, hv.w, acc);
    }
    acc += __shfl_xor(acc, 1);
    acc += __shfl_xor(acc, 2);
    acc += __shfl_xor(acc, 4);
    if (sub == 0)
      gates[rl] = acc + xgv;
    __syncthreads();

    // ---- nonlinearity + state update + publish (8 threads, no fence) ----
    if (tid < 8) {
      float gi = gates[tid],      gf = gates[8 + tid];
      float gg = gates[16 + tid], go = gates[24 + tid];
      float si = 1.f / (1.f + expf(-gi));
      float sf = 1.f / (1.f + expf(-gf));
      float so = 1.f / (1.f + expf(-go));
      float c = sf * c_sl[tid] + si * tanhf(gg);
      c_sl[tid] = c;
      float h = so * tanhf(c);
      h_all[(size_t)t * H_DIM + w * 8 + tid] = h;   // plain store for CRF phase
      unsigned long long pk = ((unsigned long long)(unsigned)t << 32) |
                              (unsigned long long)__float_as_uint(h);
      __hip_atomic_store(htag + ((t & 1) << 10) + w * 8 + tid, pk,
                         __ATOMIC_RELAXED, __HIP_MEMORY_SCOPE_AGENT);
    }
    // no trailing barrier needed: h_lds rewrite next iter is gated by the
    // gates-barrier; gates rewrite next iter is gated by the h_lds-barrier.
  }
}

// ---------------------------------------------------------------------------
// 16-lane logsumexp reduce (lanes grouped by tid&15 within a wave)
// ---------------------------------------------------------------------------
__device__ __forceinline__ float lse16(float v) {
  float m = v;
  m = fmaxf(m, __shfl_xor(m, 1));
  m = fmaxf(m, __shfl_xor(m, 2));
  m = fmaxf(m, __shfl_xor(m, 4));
  m = fmaxf(m, __shfl_xor(m, 8));
  float e = expf(v - m);
  e += __shfl_xor(e, 1);
  e += __shfl_xor(e, 2);
  e += __shfl_xor(e, 4);
  e += __shfl_xor(e, 8);
  return m + logf(e);
}

// ---------------------------------------------------------------------------
// CRF chunk kernel: per chunk c, compute feat rows s=c*64+1..c*64+64 and the
// chunk's log-semiring matrix product P_c = M_{c*64+1} x ... x M_{c*64+64}.
// M_s[i][j] = trans[i][j] + feat[s][j], feat[s] from h_all[s].
// ---------------------------------------------------------------------------
__global__ __launch_bounds__(256) void k_chunk(
    const float* __restrict__ h_all,
    const float* __restrict__ W_tag, const float* __restrict__ b_tag,
    const float* __restrict__ trans,
    float* __restrict__ featbuf,   // (T+1, 16), rows 1..T written
    float* __restrict__ Pbuf)      // (NC, 256)
{
  __shared__ float trs[16][17];
  __shared__ float featc[CLEN][16];
  __shared__ __align__(16) float hrow[H_DIM];
  __shared__ float red[16][17];
  __shared__ float Pa[16][17], Pb[16][17];

  const int tid = threadIdx.x;
  const int c = blockIdx.x;
  trs[tid >> 4][tid & 15] = trans[tid];

  // ---- feat phase ----
  const int jj = tid & 15, part = tid >> 4;
  for (int u = 0; u < CLEN; ++u) {
    int s = c * CLEN + 1 + u;
    ((float4*)hrow)[tid] = ((const float4*)(h_all + (size_t)s * H_DIM))[tid];
    __syncthreads();
    const float* wt = W_tag + (size_t)jj * H_DIM + part * 64;
    const float* hp = hrow + part * 64;
    float4 a4 = {0.f, 0.f, 0.f, 0.f};
#pragma unroll
    for (int k2 = 0; k2 < 64; k2 += 4) {
      float4 hv = *(const float4*)(hp + k2);
      float4 wv = *(const float4*)(wt + k2);
      a4.x = fmaf(hv.x, wv.x, a4.x);
      a4.y = fmaf(hv.y, wv.y, a4.y);
      a4.z = fmaf(hv.z, wv.z, a4.z);
      a4.w = fmaf(hv.w, wv.w, a4.w);
    }
    red[jj][part] = (a4.x + a4.y) + (a4.z + a4.w);
    __syncthreads();
    if (tid < 16) {
      float ssum = b_tag[tid];
#pragma unroll
      for (int pp = 0; pp < 16; ++pp) ssum += red[tid][pp];
      featc[u][tid] = ssum;
      featbuf[(size_t)s * K_TAG + tid] = ssum;
    }
    __syncthreads();
  }

  // ---- chunk product phase ----
  const int i = tid >> 4, j = tid & 15;
  Pa[i][j] = trs[i][j] + featc[0][j];
  __syncthreads();
  float* Pr = &Pa[0][0];
  float* Pw = &Pb[0][0];
  for (int u = 1; u < CLEN; ++u) {
    float fj = featc[u][j];
    float m = -3.0e38f;
#pragma unroll
    for (int k = 0; k < 16; ++k) m = fmaxf(m, Pr[i * 17 + k] + trs[k][j]);
    float e = 0.f;
#pragma unroll
    for (int k = 0; k < 16; ++k) e += expf(Pr[i * 17 + k] + trs[k][j] - m);
    Pw[i * 17 + j] = m + fj + logf(e);
    __syncthreads();
    float* tsw = Pr; Pr = Pw; Pw = tsw;
  }
  Pbuf[(size_t)c * 256 + i * 16 + j] = Pr[i * 17 + j];
}

// ---------------------------------------------------------------------------
// Sequential scan over chunk matrices (1 WG): boundary alphas + Z + alpha row 0
// ---------------------------------------------------------------------------
__global__ __launch_bounds__(256) void k_scan(
    const float* __restrict__ Pbuf,
    float* __restrict__ bbuf,      // (NC+1, 16)
    float* __restrict__ out)
{
  __shared__ float Pl[16][17];
  __shared__ float bcur[16], bnew[16];
  const int tid = threadIdx.x;
  const int i = tid & 15, j = tid >> 4;
  if (tid < 16) {
    float a0 = (tid == 0) ? 0.f : NEGINF_V;
    bcur[tid] = a0;
    bbuf[tid] = a0;
    out[1 + tid] = a0;             // alpha row 0
  }
  __syncthreads();
  for (int c = 0; c < NC; ++c) {
    Pl[tid >> 4][tid & 15] = Pbuf[(size_t)c * 256 + tid];
    __syncthreads();
    float r_ = lse16(bcur[i] + Pl[i][j]);
    if (i == 0) bnew[j] = r_;
    __syncthreads();
    if (tid < 16) {
      bcur[tid] = bnew[tid];
      bbuf[(size_t)(c + 1) * K_TAG + tid] = bnew[tid];
    }
    __syncthreads();
  }
  if (tid < 16) {
    float z = lse16(bcur[tid]);
    if (tid == 0) out[0] = z;
  }
}

// ---------------------------------------------------------------------------
// Replay within each chunk: write alpha rows s = c*64+1 .. c*64+64
// ---------------------------------------------------------------------------
__global__ __launch_bounds__(256) void k_alpha(
    const float* __restrict__ featbuf, const float* __restrict__ trans,
    const float* __restrict__ bbuf, float* __restrict__ out)
{
  __shared__ float trs[16][17];
  __shared__ float acur[16], anew[16];
  const int tid = threadIdx.x;
  const int c = blockIdx.x;
  trs[tid >> 4][tid & 15] = trans[tid];
  if (tid < 16) acur[tid] = bbuf[(size_t)c * K_TAG + tid];
  __syncthreads();
  const int i = tid & 15, j = tid >> 4;
  for (int u = 0; u < CLEN; ++u) {
    int s = c * CLEN + 1 + u;
    float v = acur[i] + trs[i][j] + featbuf[(size_t)s * K_TAG + j];
    float r_ = lse16(v);
    if (i == 0) anew[j] = r_;
    __syncthreads();
    if (tid < 16) {
      acur[tid] = anew[tid];
      out[1 + (size_t)s * K_TAG + tid] = anew[tid];
    }
    __syncthreads();
  }
}

// ---------------------------------------------------------------------------
extern "C" void kernel_launch(void* const* d_in, const int* in_sizes, int n_in,
                              void* d_out, int out_size, void* d_ws, size_t ws_size,
                              hipStream_t stream) {
  (void)in_sizes; (void)n_in; (void)out_size; (void)ws_size;
  const float* seq   = (const float*)d_in[0];
  const float* W_ih  = (const float*)d_in[1];
  const float* W_hh  = (const float*)d_in[2];
  const float* b_ih  = (const float*)d_in[3];
  const float* b_hh  = (const float*)d_in[4];
  const float* W_tag = (const float*)d_in[5];
  const float* b_tag = (const float*)d_in[6];
  const float* trans = (const float*)d_in[7];
  float* out = (float*)d_out;

  char* base = (char*)d_ws;
  size_t off = 0;
  auto take = [&](size_t nbytes) -> void* {
    void* p = base + off;
    off += (nbytes + 255) & ~(size_t)255;
    return p;
  };
  __hip_bfloat16* xg = (__hip_bfloat16*)take((size_t)T_LEN * G4 * sizeof(__hip_bfloat16));
  float* h_all   = (float*)take((size_t)(T_LEN + 1) * H_DIM * sizeof(float));
  float* featbuf = (float*)take((size_t)(T_LEN + 1) * K_TAG * sizeof(float));
  float* Pbuf    = (float*)take((size_t)NC * 256 * sizeof(float));
  float* bbuf    = (float*)take((size_t)(NC + 1) * K_TAG * sizeof(float));
  float* bsum    = (float*)take((size_t)G4 * sizeof(float));
  unsigned long long* htag = (unsigned long long*)take((size_t)2 * H_DIM * sizeof(unsigned long long));

  k_init<<<16, 256, 0, stream>>>(b_ih, b_hh, bsum, h_all, htag);
  k_gemm_xg<<<dim3(G4 / 128, T_LEN / 128), 256, 0, stream>>>(seq, W_ih, bsum, xg);
  k_lstm<<<NWG, 256, 0, stream>>>(W_hh, xg, h_all, htag);
  k_chunk<<<NC, 256, 0, stream>>>(h_all, W_tag, b_tag, trans, featbuf, Pbuf);
  k_scan<<<1, 256, 0, stream>>>(Pbuf, bbuf, out);
  k_alpha<<<NC, 256, 0, stream>>>(featbuf, trans, bbuf, out);
}